// Round 4
// baseline (441.677 us; speedup 1.0000x reference)
//
#include <hip/hip_runtime.h>

#define BIG_Z_F 1000000.0f
#define N_MESH 8

// ---------------------------------------------------------------------------
// Kernel A: per-pixel cross-mesh reduction. Reads the 8 z values, computes
// covered-count + argmin (first-win tie, matches jnp.argmin), writes the
// per-mesh mask/zb outputs and a 1-byte winner code for kernel B:
//   win = dup0 ? argmin_mesh : 0xFF   (0xFF => no duplicates at this pixel)
//
// R4: all nontemporal hints removed (single-variable A/B vs R3 — testing the
// theory that NT stores bypass L2 write-combining and cost ~50-80us).
// ---------------------------------------------------------------------------
__global__ __launch_bounds__(256) void raster_reduce(
    const float* __restrict__ zbuf,     // (N,HW)
    float* __restrict__ maskO,          // (N,HW)
    float* __restrict__ zbO,            // (N,HW)
    unsigned char* __restrict__ win,    // (HW) ws
    const int* __restrict__ mdp,        // scalar mask_duplicate
    int HW)
{
    const int pix = blockIdx.x * blockDim.x + threadIdx.x;
    if (pix >= HW) return;
    const int md = *mdp;

    float z[N_MESH];
    int count = 0;
    float best = __builtin_inff();
    int bidx = 0;
    #pragma unroll
    for (int n = 0; n < N_MESH; ++n) {
        const float zv = zbuf[n * HW + pix];
        z[n] = zv;
        count += (zv > -1.0f) ? 1 : 0;
        const float t = (zv < 0.0f) ? BIG_Z_F : zv;
        if (t < best) { best = t; bidx = n; }   // strict < => first-win tie
    }
    const bool dup0 = (count > 1);

    #pragma unroll
    for (int n = 0; n < N_MESH; ++n) {
        const int idx = n * HW + pix;
        const bool dup = dup0 && ((md != 0) || (n != bidx));
        maskO[idx] = (z[n] >= 0.0f) ? 1.0f : 0.0f;
        zbO[idx]   = dup ? -1.0f : z[n];
    }
    win[pix] = dup0 ? (unsigned char)bidx : (unsigned char)0xFF;
}

// ---------------------------------------------------------------------------
// Kernel B: per-(mesh,pixel). Gather + interpolation predicated on valid
// (~1/8 of entries).
// ---------------------------------------------------------------------------
__global__ __launch_bounds__(256) void raster_interp(
    const int*   __restrict__ p2f,      // (N,HW)
    const float* __restrict__ bary,     // (N,HW,3)
    const float* __restrict__ dists,    // (N,HW)
    const float* __restrict__ fmem,     // (F,3,C)
    const unsigned char* __restrict__ win, // (HW)
    const int*   __restrict__ mdp,      // scalar mask_duplicate
    float* __restrict__ out_map,        // (N,C,HW)
    float* __restrict__ pO,             // (N,HW)
    float* __restrict__ dO,             // (N,HW)
    float* __restrict__ bcO,            // (N,HW,3)
    int*   __restrict__ faceflag,       // (F) ws, pre-zeroed
    int HW, int C)
{
    const int pix = blockIdx.x * blockDim.x + threadIdx.x;
    if (pix >= HW) return;
    const int n   = blockIdx.y;
    const int idx = n * HW + pix;
    const int md  = *mdp;

    const unsigned char w = win[pix];
    const bool dup = (w != 0xFF) && ((md != 0) || (n != (int)w));

    const int   praw = p2f[idx];
    const float drw  = dists[idx];
    const float* bp  = bary + (size_t)idx * 3;
    const float b0r  = bp[0];
    const float b1r  = bp[1];
    const float b2r  = bp[2];

    const int   p  = dup ? -1 : praw;
    const float b0 = dup ? -1.0f : b0r;
    const float b1 = dup ? -1.0f : b1r;
    const float b2 = dup ? -1.0f : b2r;

    pO[idx] = (float)p;
    dO[idx] = dup ? -1.0f : drw;
    float* bo = bcO + (size_t)idx * 3;
    bo[0] = b0; bo[1] = b1; bo[2] = b2;

    const bool valid = (p >= 0);
    if (valid) faceflag[p] = 1;         // benign race: all store 1

    const float* a = fmem + (size_t)(valid ? p : 0) * 3 * C;
    #pragma unroll
    for (int c4 = 0; c4 < 32; c4 += 4) {    // C == 32
        float r0 = 0.0f, r1 = 0.0f, r2 = 0.0f, r3 = 0.0f;
        if (valid) {
            const float4 a0 = *(const float4*)(a + c4);
            const float4 a1 = *(const float4*)(a + C + c4);
            const float4 a2 = *(const float4*)(a + 2 * C + c4);
            r0 = b0 * a0.x + b1 * a1.x + b2 * a2.x;
            r1 = b0 * a0.y + b1 * a1.y + b2 * a2.y;
            r2 = b0 * a0.z + b1 * a1.z + b2 * a2.z;
            r3 = b0 * a0.w + b1 * a1.w + b2 * a2.w;
        }
        const int obase = (n * C + c4) * HW + pix;
        out_map[obase + 0 * HW] = r0;
        out_map[obase + 1 * HW] = r1;
        out_map[obase + 2 * HW] = r2;
        out_map[obase + 3 * HW] = r3;
    }
}

// Scatter vertex visibility from face-visibility flags.
__global__ __launch_bounds__(256) void vert_vis(
    const int* __restrict__ faceflag,
    const int* __restrict__ pfaces,     // (F,3)
    float* __restrict__ vv,             // (V), pre-zeroed
    int F)
{
    const int f = blockIdx.x * blockDim.x + threadIdx.x;
    if (f >= F) return;
    if (faceflag[f]) {
        vv[pfaces[f * 3 + 0]] = 1.0f;
        vv[pfaces[f * 3 + 1]] = 1.0f;
        vv[pfaces[f * 3 + 2]] = 1.0f;
    }
}

extern "C" void kernel_launch(void* const* d_in, const int* in_sizes, int n_in,
                              void* d_out, int out_size, void* d_ws, size_t ws_size,
                              hipStream_t stream) {
    const float* zbuf   = (const float*)d_in[0];
    const int*   p2f    = (const int*)  d_in[1];
    const float* bary   = (const float*)d_in[2];
    const float* dists  = (const float*)d_in[3];
    const float* fmem   = (const float*)d_in[4];
    const int*   pfaces = (const int*)  d_in[5];
    // d_in[6] = num_verts (device scalar; V derived from out_size instead)
    const int*   mdp    = (const int*)  d_in[7];

    const long long P  = in_sizes[0];        // N*H*W*K = 2097152
    const int HW = (int)(P / N_MESH);        // 262144 pixels
    const int F3 = in_sizes[5];              // F*3
    const int F  = F3 / 3;                   // 20000
    const int C  = in_sizes[4] / F3;         // 32
    const int V  = (int)((long long)out_size - P * C - 7 * P);  // 10002

    float* out     = (float*)d_out;
    float* out_map = out;                    // P*C
    float* vv      = out_map + P * C;        // V
    float* maskO   = vv + V;                 // P
    float* zbO     = maskO + P;              // P
    float* pO      = zbO + P;                // P
    float* dO      = pO + P;                 // P
    float* bcO     = dO + P;                 // 3P

    int* faceflag      = (int*)d_ws;                 // F ints
    unsigned char* win = (unsigned char*)(faceflag + F); // HW bytes

    hipMemsetAsync(faceflag, 0, (size_t)F * sizeof(int), stream);
    hipMemsetAsync(vv, 0, (size_t)V * sizeof(float), stream);

    const int blocks = (HW + 255) / 256;

    raster_reduce<<<dim3(blocks), dim3(256), 0, stream>>>(
        zbuf, maskO, zbO, win, mdp, HW);

    raster_interp<<<dim3(blocks, N_MESH), dim3(256), 0, stream>>>(
        p2f, bary, dists, fmem, win, mdp,
        out_map, pO, dO, bcO, faceflag, HW, C);

    vert_vis<<<dim3((F + 255) / 256), dim3(256), 0, stream>>>(
        faceflag, pfaces, vv, F);
}

// Round 6
// 413.479 us; speedup vs baseline: 1.0682x; 1.0682x over previous
//
#include <hip/hip_runtime.h>

#define BIG_Z_F 1000000.0f
#define N_MESH 8

// Native Clang vector types — required by __builtin_nontemporal_* (HIP's
// float4/int4 are structs and are rejected by the builtin).
typedef float f4 __attribute__((ext_vector_type(4)));
typedef int   i4 __attribute__((ext_vector_type(4)));
typedef unsigned char uc4 __attribute__((ext_vector_type(4)));

// R6 == R5 intent: 4 pixels per thread, 16B-wide loads/stores everywhere,
// NT hints on the big output streams (R4 A/B showed NT is worth ~15us).
// Theory: dword-width stores (40/thread) were the kernel-side limiter;
// 16B stores give fill-kernel-like burst locality (1KB/wave/instr).

// ---------------------------------------------------------------------------
// Kernel A: per-4-pixel cross-mesh reduction. win[j] = dup0 ? argmin : 0xFF.
// ---------------------------------------------------------------------------
__global__ __launch_bounds__(256) void raster_reduce(
    const f4* __restrict__ zbuf4,   // (N, HW/4)
    f4* __restrict__ maskO4,        // (N, HW/4)
    f4* __restrict__ zbO4,          // (N, HW/4)
    uc4* __restrict__ win4,         // (HW/4) ws
    const int* __restrict__ mdp,    // scalar mask_duplicate
    int HW4)
{
    const int q = blockIdx.x * blockDim.x + threadIdx.x;
    if (q >= HW4) return;
    const int md = *mdp;

    float z[N_MESH][4];
    #pragma unroll
    for (int n = 0; n < N_MESH; ++n) {
        const f4 v = __builtin_nontemporal_load(&zbuf4[n * HW4 + q]);
        z[n][0] = v.x; z[n][1] = v.y; z[n][2] = v.z; z[n][3] = v.w;
    }

    bool dup0[4]; int bidx[4];
    #pragma unroll
    for (int j = 0; j < 4; ++j) {
        int count = 0; float best = __builtin_inff(); int bi = 0;
        #pragma unroll
        for (int n = 0; n < N_MESH; ++n) {
            const float zv = z[n][j];
            count += (zv > -1.0f) ? 1 : 0;
            const float t = (zv < 0.0f) ? BIG_Z_F : zv;
            if (t < best) { best = t; bi = n; }   // strict < => first-win tie
        }
        dup0[j] = (count > 1);
        bidx[j] = bi;
    }

    #pragma unroll
    for (int n = 0; n < N_MESH; ++n) {
        f4 m, zb;
        #pragma unroll
        for (int j = 0; j < 4; ++j) {
            const bool dup = dup0[j] && ((md != 0) || (n != bidx[j]));
            m[j]  = (z[n][j] >= 0.0f) ? 1.0f : 0.0f;
            zb[j] = dup ? -1.0f : z[n][j];
        }
        __builtin_nontemporal_store(m,  &maskO4[n * HW4 + q]);
        __builtin_nontemporal_store(zb, &zbO4[n * HW4 + q]);
    }
    uc4 w;
    w.x = dup0[0] ? (unsigned char)bidx[0] : (unsigned char)0xFF;
    w.y = dup0[1] ? (unsigned char)bidx[1] : (unsigned char)0xFF;
    w.z = dup0[2] ? (unsigned char)bidx[2] : (unsigned char)0xFF;
    w.w = dup0[3] ? (unsigned char)bidx[3] : (unsigned char)0xFF;
    win4[q] = w;
}

// ---------------------------------------------------------------------------
// Kernel B: per-(mesh, 4 pixels). All outputs 16B-wide; gather+interp
// predicated per-pixel on valid (~1/8).
// ---------------------------------------------------------------------------
__global__ __launch_bounds__(256) void raster_interp(
    const i4* __restrict__ p2f4,    // (N, HW/4)
    const f4* __restrict__ bary4,   // (N, HW/4, 3)
    const f4* __restrict__ dists4,  // (N, HW/4)
    const float* __restrict__ fmem, // (F,3,C)
    const uc4* __restrict__ win4,   // (HW/4)
    const int* __restrict__ mdp,
    f4* __restrict__ out_map4,      // (N,C,HW/4)
    f4* __restrict__ pO4,           // (N, HW/4)
    f4* __restrict__ dO4,           // (N, HW/4)
    f4* __restrict__ bcO4,          // (N, HW/4, 3)
    int* __restrict__ faceflag,     // (F) ws, pre-zeroed
    int HW4, int C)
{
    const int q = blockIdx.x * blockDim.x + threadIdx.x;
    if (q >= HW4) return;
    const int n    = blockIdx.y;
    const int idx4 = n * HW4 + q;
    const int md   = *mdp;

    const uc4 wv = win4[q];
    const unsigned char w[4] = { wv.x, wv.y, wv.z, wv.w };

    const i4 praw = __builtin_nontemporal_load(&p2f4[idx4]);
    const f4 drw  = __builtin_nontemporal_load(&dists4[idx4]);
    const f4 bv0  = __builtin_nontemporal_load(&bary4[idx4 * 3 + 0]); // p0.xyz p1.x
    const f4 bv1  = __builtin_nontemporal_load(&bary4[idx4 * 3 + 1]); // p1.yz  p2.xy
    const f4 bv2  = __builtin_nontemporal_load(&bary4[idx4 * 3 + 2]); // p2.z   p3.xyz
    const int   pr[4] = { praw.x, praw.y, praw.z, praw.w };
    const float dr[4] = { drw.x, drw.y, drw.z, drw.w };
    const float br[4][3] = {
        { bv0.x, bv0.y, bv0.z },
        { bv0.w, bv1.x, bv1.y },
        { bv1.z, bv1.w, bv2.x },
        { bv2.y, bv2.z, bv2.w },
    };

    bool  valid[4];
    int   p[4];
    float b[4][3];
    f4 pOv, dOv;
    #pragma unroll
    for (int j = 0; j < 4; ++j) {
        const bool dup = (w[j] != 0xFF) && ((md != 0) || (n != (int)w[j]));
        p[j] = dup ? -1 : pr[j];
        valid[j] = (p[j] >= 0);
        b[j][0] = dup ? -1.0f : br[j][0];
        b[j][1] = dup ? -1.0f : br[j][1];
        b[j][2] = dup ? -1.0f : br[j][2];
        pOv[j] = (float)p[j];
        dOv[j] = dup ? -1.0f : dr[j];
        if (valid[j]) faceflag[p[j]] = 1;    // benign race: all store 1
    }
    __builtin_nontemporal_store(pOv, &pO4[idx4]);
    __builtin_nontemporal_store(dOv, &dO4[idx4]);
    {
        f4 c0, c1, c2;
        c0.x = b[0][0]; c0.y = b[0][1]; c0.z = b[0][2]; c0.w = b[1][0];
        c1.x = b[1][1]; c1.y = b[1][2]; c1.z = b[2][0]; c1.w = b[2][1];
        c2.x = b[2][2]; c2.y = b[3][0]; c2.z = b[3][1]; c2.w = b[3][2];
        __builtin_nontemporal_store(c0, &bcO4[idx4 * 3 + 0]);
        __builtin_nontemporal_store(c1, &bcO4[idx4 * 3 + 1]);
        __builtin_nontemporal_store(c2, &bcO4[idx4 * 3 + 2]);
    }

    const float* ab[4];
    #pragma unroll
    for (int j = 0; j < 4; ++j)
        ab[j] = fmem + (size_t)(valid[j] ? p[j] : 0) * 3 * C;

    #pragma unroll
    for (int c4 = 0; c4 < 32; c4 += 4) {     // C == 32
        float acc[4][4];                      // [channel k][pixel j]
        #pragma unroll
        for (int k = 0; k < 4; ++k)
            #pragma unroll
            for (int j = 0; j < 4; ++j)
                acc[k][j] = 0.0f;

        #pragma unroll
        for (int j = 0; j < 4; ++j) {
            if (valid[j]) {                   // exec-masked gather
                const float* a = ab[j];
                const f4 a0 = *(const f4*)(a + c4);
                const f4 a1 = *(const f4*)(a + C + c4);
                const f4 a2 = *(const f4*)(a + 2 * C + c4);
                acc[0][j] = b[j][0] * a0.x + b[j][1] * a1.x + b[j][2] * a2.x;
                acc[1][j] = b[j][0] * a0.y + b[j][1] * a1.y + b[j][2] * a2.y;
                acc[2][j] = b[j][0] * a0.z + b[j][1] * a1.z + b[j][2] * a2.z;
                acc[3][j] = b[j][0] * a0.w + b[j][1] * a1.w + b[j][2] * a2.w;
            }
        }
        #pragma unroll
        for (int k = 0; k < 4; ++k) {
            f4 r;
            r.x = acc[k][0]; r.y = acc[k][1]; r.z = acc[k][2]; r.w = acc[k][3];
            __builtin_nontemporal_store(r, &out_map4[(size_t)(n * C + c4 + k) * HW4 + q]);
        }
    }
}

// Scatter vertex visibility from face-visibility flags.
__global__ __launch_bounds__(256) void vert_vis(
    const int* __restrict__ faceflag,
    const int* __restrict__ pfaces,     // (F,3)
    float* __restrict__ vv,             // (V), pre-zeroed
    int F)
{
    const int f = blockIdx.x * blockDim.x + threadIdx.x;
    if (f >= F) return;
    if (faceflag[f]) {
        vv[pfaces[f * 3 + 0]] = 1.0f;
        vv[pfaces[f * 3 + 1]] = 1.0f;
        vv[pfaces[f * 3 + 2]] = 1.0f;
    }
}

extern "C" void kernel_launch(void* const* d_in, const int* in_sizes, int n_in,
                              void* d_out, int out_size, void* d_ws, size_t ws_size,
                              hipStream_t stream) {
    const float* zbuf   = (const float*)d_in[0];
    const int*   p2f    = (const int*)  d_in[1];
    const float* bary   = (const float*)d_in[2];
    const float* dists  = (const float*)d_in[3];
    const float* fmem   = (const float*)d_in[4];
    const int*   pfaces = (const int*)  d_in[5];
    // d_in[6] = num_verts (device scalar; V derived from out_size instead)
    const int*   mdp    = (const int*)  d_in[7];

    const long long P  = in_sizes[0];        // N*H*W*K = 2097152
    const int HW  = (int)(P / N_MESH);       // 262144 pixels
    const int HW4 = HW / 4;                  // 65536
    const int F3  = in_sizes[5];             // F*3
    const int F   = F3 / 3;                  // 20000
    const int C   = in_sizes[4] / F3;        // 32
    const int V   = (int)((long long)out_size - P * C - 7 * P);  // 10002

    float* out     = (float*)d_out;
    float* out_map = out;                    // P*C
    float* vv      = out_map + P * C;        // V
    float* maskO   = vv + V;                 // P
    float* zbO     = maskO + P;              // P
    float* pO      = zbO + P;                // P
    float* dO      = pO + P;                 // P
    float* bcO     = dO + P;                 // 3P

    int* faceflag = (int*)d_ws;                 // F ints
    uc4* win4     = (uc4*)(faceflag + F);       // HW bytes (4B-aligned)

    (void)hipMemsetAsync(faceflag, 0, (size_t)F * sizeof(int), stream);
    (void)hipMemsetAsync(vv, 0, (size_t)V * sizeof(float), stream);

    raster_reduce<<<dim3(HW4 / 256), dim3(256), 0, stream>>>(
        (const f4*)zbuf, (f4*)maskO, (f4*)zbO, win4, mdp, HW4);

    raster_interp<<<dim3(HW4 / 256, N_MESH), dim3(256), 0, stream>>>(
        (const i4*)p2f, (const f4*)bary, (const f4*)dists, fmem,
        (const uc4*)win4, mdp,
        (f4*)out_map, (f4*)pO, (f4*)dO, (f4*)bcO,
        faceflag, HW4, C);

    vert_vis<<<dim3((F + 255) / 256), dim3(256), 0, stream>>>(
        faceflag, pfaces, vv, F);
}

// Round 7
// 394.504 us; speedup vs baseline: 1.1196x; 1.0481x over previous
//
#include <hip/hip_runtime.h>

#define BIG_Z_F 1000000.0f
#define N_MESH 8

// Native Clang vector types — required by __builtin_nontemporal_* (HIP's
// float4/int4 are structs and are rejected by the builtin).
typedef float f4 __attribute__((ext_vector_type(4)));
typedef int   i4 __attribute__((ext_vector_type(4)));
typedef unsigned char uc4 __attribute__((ext_vector_type(4)));

// R7: branchless gather. R6's interp loop had 32 exec-masked regions/thread
// (8 c4-iters x 4 pixels) each with 3 dependent ~200cyc L2 loads that the
// backend can't hoist across s_and_saveexec — theory: that serialization is
// the ~80us gap vs roofline. Fix: always-load with address-select
// (safe = valid?p:0, ~0.8GB L2 traffic, cheap) and zero compute-coefficients
// for invalid pixels so out = sum(b*a) = 0 with no branch at all.

// ---------------------------------------------------------------------------
// Kernel A: per-4-pixel cross-mesh reduction. win[j] = dup0 ? argmin : 0xFF.
// ---------------------------------------------------------------------------
__global__ __launch_bounds__(256) void raster_reduce(
    const f4* __restrict__ zbuf4,   // (N, HW/4)
    f4* __restrict__ maskO4,        // (N, HW/4)
    f4* __restrict__ zbO4,          // (N, HW/4)
    uc4* __restrict__ win4,         // (HW/4) ws
    const int* __restrict__ mdp,    // scalar mask_duplicate
    int HW4)
{
    const int q = blockIdx.x * blockDim.x + threadIdx.x;
    if (q >= HW4) return;
    const int md = *mdp;

    float z[N_MESH][4];
    #pragma unroll
    for (int n = 0; n < N_MESH; ++n) {
        const f4 v = __builtin_nontemporal_load(&zbuf4[n * HW4 + q]);
        z[n][0] = v.x; z[n][1] = v.y; z[n][2] = v.z; z[n][3] = v.w;
    }

    bool dup0[4]; int bidx[4];
    #pragma unroll
    for (int j = 0; j < 4; ++j) {
        int count = 0; float best = __builtin_inff(); int bi = 0;
        #pragma unroll
        for (int n = 0; n < N_MESH; ++n) {
            const float zv = z[n][j];
            count += (zv > -1.0f) ? 1 : 0;
            const float t = (zv < 0.0f) ? BIG_Z_F : zv;
            if (t < best) { best = t; bi = n; }   // strict < => first-win tie
        }
        dup0[j] = (count > 1);
        bidx[j] = bi;
    }

    #pragma unroll
    for (int n = 0; n < N_MESH; ++n) {
        f4 m, zb;
        #pragma unroll
        for (int j = 0; j < 4; ++j) {
            const bool dup = dup0[j] && ((md != 0) || (n != bidx[j]));
            m[j]  = (z[n][j] >= 0.0f) ? 1.0f : 0.0f;
            zb[j] = dup ? -1.0f : z[n][j];
        }
        __builtin_nontemporal_store(m,  &maskO4[n * HW4 + q]);
        __builtin_nontemporal_store(zb, &zbO4[n * HW4 + q]);
    }
    uc4 w;
    w.x = dup0[0] ? (unsigned char)bidx[0] : (unsigned char)0xFF;
    w.y = dup0[1] ? (unsigned char)bidx[1] : (unsigned char)0xFF;
    w.z = dup0[2] ? (unsigned char)bidx[2] : (unsigned char)0xFF;
    w.w = dup0[3] ? (unsigned char)bidx[3] : (unsigned char)0xFF;
    win4[q] = w;
}

// ---------------------------------------------------------------------------
// Kernel B: per-(mesh, 4 pixels). Fully branchless: no exec-mask regions in
// the gather/interp path. All outputs 16B NT stores.
// ---------------------------------------------------------------------------
__global__ __launch_bounds__(256) void raster_interp(
    const i4* __restrict__ p2f4,    // (N, HW/4)
    const f4* __restrict__ bary4,   // (N, HW/4, 3)
    const f4* __restrict__ dists4,  // (N, HW/4)
    const float* __restrict__ fmem, // (F,3,C)
    const uc4* __restrict__ win4,   // (HW/4)
    const int* __restrict__ mdp,
    f4* __restrict__ out_map4,      // (N,C,HW/4)
    f4* __restrict__ pO4,           // (N, HW/4)
    f4* __restrict__ dO4,           // (N, HW/4)
    f4* __restrict__ bcO4,          // (N, HW/4, 3)
    int* __restrict__ faceflag,     // (F+1) ws, pre-zeroed; slot F = dummy
    int HW4, int C, int F)
{
    const int q = blockIdx.x * blockDim.x + threadIdx.x;
    if (q >= HW4) return;
    const int n    = blockIdx.y;
    const int idx4 = n * HW4 + q;
    const int md   = *mdp;

    const uc4 wv = win4[q];
    const unsigned char w[4] = { wv.x, wv.y, wv.z, wv.w };

    const i4 praw = __builtin_nontemporal_load(&p2f4[idx4]);
    const f4 drw  = __builtin_nontemporal_load(&dists4[idx4]);
    const f4 bv0  = __builtin_nontemporal_load(&bary4[idx4 * 3 + 0]); // p0.xyz p1.x
    const f4 bv1  = __builtin_nontemporal_load(&bary4[idx4 * 3 + 1]); // p1.yz  p2.xy
    const f4 bv2  = __builtin_nontemporal_load(&bary4[idx4 * 3 + 2]); // p2.z   p3.xyz
    const int   pr[4] = { praw.x, praw.y, praw.z, praw.w };
    const float dr[4] = { drw.x, drw.y, drw.z, drw.w };
    const float br[4][3] = {
        { bv0.x, bv0.y, bv0.z },
        { bv0.w, bv1.x, bv1.y },
        { bv1.z, bv1.w, bv2.x },
        { bv2.y, bv2.z, bv2.w },
    };

    float bst[4][3];   // values stored to bcO (dup -> -1)
    float bc[4][3];    // compute coefficients (invalid -> 0 => out = 0)
    int   safe[4];
    f4 pOv, dOv;
    #pragma unroll
    for (int j = 0; j < 4; ++j) {
        const bool dup   = (w[j] != 0xFF) && ((md != 0) || (n != (int)w[j]));
        const int  p     = dup ? -1 : pr[j];
        const bool valid = (p >= 0);
        #pragma unroll
        for (int k = 0; k < 3; ++k) {
            bst[j][k] = dup ? -1.0f : br[j][k];
            bc[j][k]  = valid ? bst[j][k] : 0.0f;
        }
        safe[j] = valid ? p : 0;
        pOv[j]  = (float)p;
        dOv[j]  = dup ? -1.0f : dr[j];
        faceflag[valid ? p : F] = 1;   // branchless scatter; slot F = dummy
    }
    __builtin_nontemporal_store(pOv, &pO4[idx4]);
    __builtin_nontemporal_store(dOv, &dO4[idx4]);
    {
        f4 c0, c1, c2;
        c0.x = bst[0][0]; c0.y = bst[0][1]; c0.z = bst[0][2]; c0.w = bst[1][0];
        c1.x = bst[1][1]; c1.y = bst[1][2]; c1.z = bst[2][0]; c1.w = bst[2][1];
        c2.x = bst[2][2]; c2.y = bst[3][0]; c2.z = bst[3][1]; c2.w = bst[3][2];
        __builtin_nontemporal_store(c0, &bcO4[idx4 * 3 + 0]);
        __builtin_nontemporal_store(c1, &bcO4[idx4 * 3 + 1]);
        __builtin_nontemporal_store(c2, &bcO4[idx4 * 3 + 2]);
    }

    const float* ab[4];
    #pragma unroll
    for (int j = 0; j < 4; ++j)
        ab[j] = fmem + (size_t)safe[j] * 3 * C;

    #pragma unroll
    for (int c4 = 0; c4 < 32; c4 += 4) {     // C == 32
        f4 r[4];   // r[j] = channels c4..c4+3 of pixel j (channel-major)
        #pragma unroll
        for (int j = 0; j < 4; ++j) {
            const float* a = ab[j];
            const f4 a0 = *(const f4*)(a + c4);
            const f4 a1 = *(const f4*)(a + C + c4);
            const f4 a2 = *(const f4*)(a + 2 * C + c4);
            r[j] = bc[j][0] * a0 + bc[j][1] * a1 + bc[j][2] * a2;
        }
        #pragma unroll
        for (int k = 0; k < 4; ++k) {        // transpose to pixel-major
            f4 o;
            o.x = r[0][k]; o.y = r[1][k]; o.z = r[2][k]; o.w = r[3][k];
            __builtin_nontemporal_store(o, &out_map4[(size_t)(n * C + c4 + k) * HW4 + q]);
        }
    }
}

// Scatter vertex visibility from face-visibility flags.
__global__ __launch_bounds__(256) void vert_vis(
    const int* __restrict__ faceflag,
    const int* __restrict__ pfaces,     // (F,3)
    float* __restrict__ vv,             // (V), pre-zeroed
    int F)
{
    const int f = blockIdx.x * blockDim.x + threadIdx.x;
    if (f >= F) return;
    if (faceflag[f]) {
        vv[pfaces[f * 3 + 0]] = 1.0f;
        vv[pfaces[f * 3 + 1]] = 1.0f;
        vv[pfaces[f * 3 + 2]] = 1.0f;
    }
}

extern "C" void kernel_launch(void* const* d_in, const int* in_sizes, int n_in,
                              void* d_out, int out_size, void* d_ws, size_t ws_size,
                              hipStream_t stream) {
    const float* zbuf   = (const float*)d_in[0];
    const int*   p2f    = (const int*)  d_in[1];
    const float* bary   = (const float*)d_in[2];
    const float* dists  = (const float*)d_in[3];
    const float* fmem   = (const float*)d_in[4];
    const int*   pfaces = (const int*)  d_in[5];
    // d_in[6] = num_verts (device scalar; V derived from out_size instead)
    const int*   mdp    = (const int*)  d_in[7];

    const long long P  = in_sizes[0];        // N*H*W*K = 2097152
    const int HW  = (int)(P / N_MESH);       // 262144 pixels
    const int HW4 = HW / 4;                  // 65536
    const int F3  = in_sizes[5];             // F*3
    const int F   = F3 / 3;                  // 20000
    const int C   = in_sizes[4] / F3;        // 32
    const int V   = (int)((long long)out_size - P * C - 7 * P);  // 10002

    float* out     = (float*)d_out;
    float* out_map = out;                    // P*C
    float* vv      = out_map + P * C;        // V
    float* maskO   = vv + V;                 // P
    float* zbO     = maskO + P;              // P
    float* pO      = zbO + P;                // P
    float* dO      = pO + P;                 // P
    float* bcO     = dO + P;                 // 3P

    int* faceflag = (int*)d_ws;                 // F+1 ints (slot F = dummy)
    uc4* win4     = (uc4*)(faceflag + F + 4);   // HW bytes, 16B-aligned-ish

    (void)hipMemsetAsync(faceflag, 0, (size_t)(F + 1) * sizeof(int), stream);
    (void)hipMemsetAsync(vv, 0, (size_t)V * sizeof(float), stream);

    raster_reduce<<<dim3(HW4 / 256), dim3(256), 0, stream>>>(
        (const f4*)zbuf, (f4*)maskO, (f4*)zbO, win4, mdp, HW4);

    raster_interp<<<dim3(HW4 / 256, N_MESH), dim3(256), 0, stream>>>(
        (const i4*)p2f, (const f4*)bary, (const f4*)dists, fmem,
        (const uc4*)win4, mdp,
        (f4*)out_map, (f4*)pO, (f4*)dO, (f4*)bcO,
        faceflag, HW4, C, F);

    vert_vis<<<dim3((F + 255) / 256), dim3(256), 0, stream>>>(
        faceflag, pfaces, vv, F);
}